// Round 1
// baseline (408.324 us; speedup 1.0000x reference)
//
#include <hip/hip_runtime.h>
#include <cmath>

// Problem constants (from reference setup_inputs)
#define BN_EPS 1e-6f
constexpr int B_     = 4;
constexpr int N_     = 16384;
constexpr int K_     = 16;
constexpr int C_IMG  = 54;     // image feature channels
constexpr int C1     = 64;     // conv1 input channels (3+3+3+1+54)
constexpr int CO     = 32;     // conv1/conv2 output channels
constexpr int C2     = 70;     // conv2 input channels (35 max + 35 mean)
constexpr int NT     = 16;     // n-tile per block
constexpr int HPAD   = 17;     // h LDS inner pad (k dim 16 -> 17)
constexpr int PPAD   = 76;     // pooled LDS row pad (70 -> 76, 16B-aligned, 2-way banks)

// One block: (b, tile of NT=16 points). 256 threads.
// Phase A: thread=(ln,k) builds x[64], conv1+bn1+relu -> h LDS.
// Phase B1: thread=(n,c) reduces over k -> pooled LDS (max | mean).
// Phase B2: thread=(n,o) conv2+bn2+relu -> out.
__global__ __launch_bounds__(256, 4) void pif_fused_kernel(
    const float* __restrict__ points,   // (B,N,3)
    const float* __restrict__ imgf,     // (B,54,N,K)
    const float* __restrict__ dist,     // (B,N,K)
    const int*   __restrict__ idx,      // (B,N,K)
    const float* __restrict__ w1,       // (32,64)
    const float* __restrict__ b1,
    const float* __restrict__ g1,
    const float* __restrict__ be1,
    const float* __restrict__ m1,
    const float* __restrict__ v1,
    const float* __restrict__ w2,       // (32,70)
    const float* __restrict__ b2,
    const float* __restrict__ g2,
    const float* __restrict__ be2,
    const float* __restrict__ m2,
    const float* __restrict__ v2,
    float* __restrict__ out)            // (B,32,N)
{
    __shared__ float h_lds[CO][NT * HPAD];   // 32*272*4 = 34816 B
    __shared__ float pooled[NT][PPAD];       // 16*76*4  =  4864 B  (total 39680 B -> 4 blocks/CU)

    const int t    = threadIdx.x;
    const int tpb  = N_ / NT;                // tiles per batch
    const int b    = blockIdx.x / tpb;
    const int n0   = (blockIdx.x % tpb) * NT;

    const int k    = t & 15;
    const int ln   = t >> 4;
    const int n    = n0 + ln;

    // ---------------- Phase A ----------------
    float x[C1];

    // extended point (broadcast over k; L1-cached)
    const int pbase = (b * N_ + n) * 3;
    const float px = points[pbase + 0];
    const float py = points[pbase + 1];
    const float pz = points[pbase + 2];

    // KNN gather
    const int j  = idx[(b * N_ + n) * K_ + k];
    const int qb = (b * N_ + j) * 3;
    const float qx = points[qb + 0];
    const float qy = points[qb + 1];
    const float qz = points[qb + 2];

    x[0] = px;      x[1] = py;      x[2] = pz;
    x[3] = qx;      x[4] = qy;      x[5] = qz;
    x[6] = px - qx; x[7] = py - qy; x[8] = pz - qz;
    x[9] = dist[(b * N_ + n) * K_ + k];

    {
        const float* p = imgf + ((b * C_IMG) * N_ + n) * K_ + k;
        #pragma unroll
        for (int c = 0; c < C_IMG; ++c)
            x[10 + c] = p[c * (N_ * K_)];    // stride 1 MB apart per c; coalesced per wave
    }

    // conv1 + bn1 + relu; w1/bn-constant indices are wave-uniform -> s_load
    #pragma unroll 2
    for (int o = 0; o < CO; ++o) {
        const float* wr = w1 + o * C1;
        float a0 = 0.f, a1 = 0.f;            // 2 chains to hide fma latency
        #pragma unroll
        for (int c = 0; c < C1; c += 2) {
            a0 = fmaf(wr[c],     x[c],     a0);
            a1 = fmaf(wr[c + 1], x[c + 1], a1);
        }
        const float acc = a0 + a1;
        const float inv = g1[o] * rsqrtf(v1[o] + BN_EPS);
        float hv = (acc + b1[o]) * inv + (be1[o] - m1[o] * inv);
        hv = fmaxf(hv, 0.f);
        h_lds[o][ln * HPAD + k] = hv;
    }
    __syncthreads();

    // ---------------- Phase B1: pool over k ----------------
    #pragma unroll
    for (int r = 0; r < 2; ++r) {
        const int nn = t & 15;
        const int c  = (t >> 4) + r * 16;    // h channel 0..31
        float mx = 0.f;                      // h >= 0 after relu
        float sm = 0.f;
        #pragma unroll
        for (int kk = 0; kk < K_; ++kk) {
            const float v = h_lds[c][nn * HPAD + kk];
            mx = fmaxf(mx, v);
            sm += v;
        }
        pooled[nn][c]      = mx;
        pooled[nn][35 + c] = sm * (1.f / 16.f);
    }
    if (t < 48) {                            // ep channels: max == mean == value
        const int nn = t & 15;
        const int jj = t >> 4;               // 0..2
        const float v = points[(b * N_ + n0 + nn) * 3 + jj];
        pooled[nn][32 + jj] = v;
        pooled[nn][67 + jj] = v;
    }
    __syncthreads();

    // ---------------- Phase B2: conv2 + bn2 + relu ----------------
    #pragma unroll
    for (int r = 0; r < 2; ++r) {
        const int nn = t & 15;
        const int o  = (t >> 4) + r * 16;    // 0..31
        const float* wr = w2 + o * C2;       // per-16-lane-group row; L1-resident
        float a0 = 0.f, a1 = 0.f;
        #pragma unroll
        for (int c = 0; c < C2; c += 2) {
            a0 = fmaf(wr[c],     pooled[nn][c],     a0);
            a1 = fmaf(wr[c + 1], pooled[nn][c + 1], a1);
        }
        const float acc = a0 + a1;
        const float inv = g2[o] * rsqrtf(v2[o] + BN_EPS);
        float ov = (acc + b2[o]) * inv + (be2[o] - m2[o] * inv);
        ov = fmaxf(ov, 0.f);
        out[(b * CO + o) * N_ + n0 + nn] = ov;  // 16 consecutive floats per lane-group
    }
}

extern "C" void kernel_launch(void* const* d_in, const int* in_sizes, int n_in,
                              void* d_out, int out_size, void* d_ws, size_t ws_size,
                              hipStream_t stream) {
    const float* points = (const float*)d_in[0];
    const float* imgf   = (const float*)d_in[1];
    const float* dist   = (const float*)d_in[2];
    const int*   idx    = (const int*)  d_in[3];
    const float* w1     = (const float*)d_in[4];
    const float* b1     = (const float*)d_in[5];
    const float* g1     = (const float*)d_in[6];
    const float* be1    = (const float*)d_in[7];
    const float* m1     = (const float*)d_in[8];
    const float* v1     = (const float*)d_in[9];
    const float* w2     = (const float*)d_in[10];
    const float* b2     = (const float*)d_in[11];
    const float* g2     = (const float*)d_in[12];
    const float* be2    = (const float*)d_in[13];
    const float* m2     = (const float*)d_in[14];
    const float* v2     = (const float*)d_in[15];
    float* out          = (float*)d_out;

    const int blocks = B_ * (N_ / NT);       // 4096
    pif_fused_kernel<<<blocks, 256, 0, stream>>>(
        points, imgf, dist, idx,
        w1, b1, g1, be1, m1, v1,
        w2, b2, g2, be2, m2, v2, out);
}

// Round 2
// 400.406 us; speedup vs baseline: 1.0198x; 1.0198x over previous
//
#include <hip/hip_runtime.h>
#include <cmath>

// Problem constants (from reference setup_inputs)
#define BN_EPS 1e-6f
constexpr int B_     = 4;
constexpr int N_     = 16384;
constexpr int K_     = 16;
constexpr int C_IMG  = 54;     // image feature channels
constexpr int C1     = 64;     // conv1 input channels (3+3+3+1+54)
constexpr int CO     = 32;     // conv1/conv2 output channels
constexpr int C2     = 70;     // conv2 input channels (35 max + 35 mean)
constexpr int NT     = 16;     // n-tile per block
constexpr int HPAD   = 17;     // h LDS inner pad (k dim 16 -> 17)
constexpr int PPAD   = 76;     // pooled LDS row pad (70 -> 76; 76%32=12 -> 2-way banks, free)
constexpr int NK     = N_ * K_;
constexpr int CHUNK  = 6;      // imgf channels per register chunk (54 = 9*6)

// One block: (b, tile of NT=16 points). 256 threads.
// Phase A: thread=(ln,k). Chunked conv1: acc[32] stays live, image-feature
//          channels stream through xv[CHUNK] -> no x[64] register array, no
//          scratch spill (R1 post-mortem: spills caused 41 MB scratch writes).
// Phase B1: thread=(n,c) reduces over k -> pooled LDS (max | mean).
// Phase B2: thread=(n,o) conv2+bn2+relu -> out.
__global__ __launch_bounds__(256, 4) void pif_fused_kernel(
    const float* __restrict__ points,   // (B,N,3)
    const float* __restrict__ imgf,     // (B,54,N,K)
    const float* __restrict__ dist,     // (B,N,K)
    const int*   __restrict__ idx,      // (B,N,K)
    const float* __restrict__ w1,       // (32,64)
    const float* __restrict__ b1,
    const float* __restrict__ g1,
    const float* __restrict__ be1,
    const float* __restrict__ m1,
    const float* __restrict__ v1,
    const float* __restrict__ w2,       // (32,70)
    const float* __restrict__ b2,
    const float* __restrict__ g2,
    const float* __restrict__ be2,
    const float* __restrict__ m2,
    const float* __restrict__ v2,
    float* __restrict__ out)            // (B,32,N)
{
    __shared__ float h_lds[CO][NT * HPAD];   // 34816 B
    __shared__ float pooled[NT][PPAD];       //  4864 B (total 39680 -> 4 blocks/CU)

    const int t    = threadIdx.x;
    const int tpb  = N_ / NT;
    const int b    = blockIdx.x / tpb;
    const int n0   = (blockIdx.x % tpb) * NT;

    const int k    = t & 15;
    const int ln   = t >> 4;
    const int n    = n0 + ln;

    // ---------------- Phase A ----------------
    // Issue the dependent-chain loads (idx -> gather) first.
    const int   base_nk = (b * N_ + n) * K_ + k;
    const int   j  = idx[base_nk];
    const float dv = dist[base_nk];

    const int pbase = (b * N_ + n) * 3;
    const float px = points[pbase + 0];
    const float py = points[pbase + 1];
    const float pz = points[pbase + 2];
    const int qb = (b * N_ + j) * 3;
    const float qx = points[qb + 0];
    const float qy = points[qb + 1];
    const float qz = points[qb + 2];

    float g[10];
    g[0] = px;      g[1] = py;      g[2] = pz;
    g[3] = qx;      g[4] = qy;      g[5] = qz;
    g[6] = px - qx; g[7] = py - qy; g[8] = pz - qz;
    g[9] = dv;

    // Geometry contribution (channels 0..9); w1 indices wave-uniform -> s_load.
    float acc[CO];
    #pragma unroll
    for (int o = 0; o < CO; ++o) {
        const float* wr = w1 + o * C1;
        float a0 = 0.f, a1 = 0.f;
        #pragma unroll
        for (int c = 0; c < 10; c += 2) {
            a0 = fmaf(wr[c],     g[c],     a0);
            a1 = fmaf(wr[c + 1], g[c + 1], a1);
        }
        acc[o] = a0 + a1;
    }

    // Image-feature channels 10..63 in chunks of CHUNK: xv is consumed before
    // the next chunk's loads must land -> bounded register pressure.
    const float* ip = imgf + (size_t)b * C_IMG * NK + (n * K_ + k);
    #pragma unroll
    for (int c0 = 0; c0 < C_IMG; c0 += CHUNK) {
        float xv[CHUNK];
        #pragma unroll
        for (int jj = 0; jj < CHUNK; ++jj)
            xv[jj] = ip[(c0 + jj) * NK];     // coalesced: 64 consecutive (n,k) per wave
        #pragma unroll
        for (int o = 0; o < CO; ++o) {
            const float* wr = w1 + o * C1 + 10 + c0;
            #pragma unroll
            for (int jj = 0; jj < CHUNK; ++jj)
                acc[o] = fmaf(wr[jj], xv[jj], acc[o]);
        }
    }

    // BN1 + ReLU epilogue -> h LDS
    #pragma unroll
    for (int o = 0; o < CO; ++o) {
        const float inv = g1[o] * rsqrtf(v1[o] + BN_EPS);
        float hv = fmaf(acc[o] + b1[o], inv, be1[o] - m1[o] * inv);
        hv = fmaxf(hv, 0.f);
        h_lds[o][ln * HPAD + k] = hv;
    }
    __syncthreads();

    // ---------------- Phase B1: pool over k ----------------
    #pragma unroll
    for (int r = 0; r < 2; ++r) {
        const int nn = t & 15;
        const int c  = (t >> 4) + r * 16;    // h channel 0..31
        float mx = 0.f;                      // h >= 0 after relu
        float sm = 0.f;
        #pragma unroll
        for (int kk = 0; kk < K_; ++kk) {
            const float v = h_lds[c][nn * HPAD + kk];
            mx = fmaxf(mx, v);
            sm += v;
        }
        pooled[nn][c]      = mx;
        pooled[nn][35 + c] = sm * (1.f / 16.f);
    }
    if (t < 48) {                            // ep channels: max == mean == value
        const int nn = t & 15;
        const int jj = t >> 4;               // 0..2
        const float v = points[(b * N_ + n0 + nn) * 3 + jj];
        pooled[nn][32 + jj] = v;
        pooled[nn][67 + jj] = v;
    }
    __syncthreads();

    // ---------------- Phase B2: conv2 + bn2 + relu ----------------
    #pragma unroll
    for (int r = 0; r < 2; ++r) {
        const int nn = t & 15;
        const int o  = (t >> 4) + r * 16;    // 0..31 (lane-varying; w2 is L1-resident, 8.75 KB)
        const float* wr = w2 + o * C2;
        float a0 = 0.f, a1 = 0.f;
        #pragma unroll
        for (int c = 0; c < C2; c += 2) {
            a0 = fmaf(wr[c],     pooled[nn][c],     a0);
            a1 = fmaf(wr[c + 1], pooled[nn][c + 1], a1);
        }
        const float acc2 = a0 + a1;
        const float inv = g2[o] * rsqrtf(v2[o] + BN_EPS);
        float ov = fmaf(acc2 + b2[o], inv, be2[o] - m2[o] * inv);
        ov = fmaxf(ov, 0.f);
        out[(b * CO + o) * N_ + n0 + nn] = ov;
    }
}

extern "C" void kernel_launch(void* const* d_in, const int* in_sizes, int n_in,
                              void* d_out, int out_size, void* d_ws, size_t ws_size,
                              hipStream_t stream) {
    const float* points = (const float*)d_in[0];
    const float* imgf   = (const float*)d_in[1];
    const float* dist   = (const float*)d_in[2];
    const int*   idx    = (const int*)  d_in[3];
    const float* w1     = (const float*)d_in[4];
    const float* b1     = (const float*)d_in[5];
    const float* g1     = (const float*)d_in[6];
    const float* be1    = (const float*)d_in[7];
    const float* m1     = (const float*)d_in[8];
    const float* v1     = (const float*)d_in[9];
    const float* w2     = (const float*)d_in[10];
    const float* b2     = (const float*)d_in[11];
    const float* g2     = (const float*)d_in[12];
    const float* be2    = (const float*)d_in[13];
    const float* m2     = (const float*)d_in[14];
    const float* v2     = (const float*)d_in[15];
    float* out          = (float*)d_out;

    const int blocks = B_ * (N_ / NT);       // 4096
    pif_fused_kernel<<<blocks, 256, 0, stream>>>(
        points, imgf, dist, idx,
        w1, b1, g1, be1, m1, v1,
        w2, b2, g2, be2, m2, v2, out);
}

// Round 3
// 356.324 us; speedup vs baseline: 1.1459x; 1.1237x over previous
//
#include <hip/hip_runtime.h>
#include <hip/hip_bf16.h>
#include <cmath>

#define BN_EPS 1e-6f
typedef unsigned int u32;
typedef __attribute__((ext_vector_type(8))) short short8;   // 8 bf16 (4 VGPRs)
typedef __attribute__((ext_vector_type(4))) float f32x4;    // MFMA accum

constexpr int B_    = 4;
constexpr int N_    = 16384;
constexpr int K_    = 16;
constexpr int C_IMG = 54;
constexpr int C1    = 64;     // concat channels
constexpr int CO    = 32;
constexpr int C2    = 70;
constexpr int NT    = 16;     // n per block
constexpr int POS   = 256;    // positions (n,k) per block
constexpr int XSTR  = 34;     // x_lds row stride in dwords (32 data + 2 pad)
                              // stride 34: b32 writes 4-way (1.58x), b64 reads ~4-way, b64-aligned
constexpr int PPAD  = 76;
constexpr int NK    = N_ * K_;
constexpr int CHUNK = 6;

__device__ inline u32 pkbf(float a, float b) {      // pack 2 fp32 -> 2 bf16 (RNE), a in low half
    union { __hip_bfloat162 h; u32 u; } cv;
    cv.h = __float22bfloat162_rn(make_float2(a, b));
    return cv.u;
}

// Block = (b, 16-n tile) = 256 positions. Phase A: build bf16 concat X in LDS.
// Phase M: 4 waves x 16 mfma_f32_16x16x32_bf16 -> h (D: col=lane&15=o, row=quad*4+reg=k),
//          BN1+ReLU in D-frag, pool over k via reg-reduce + shfl_xor(16,32) -> pooled LDS.
// Phase C: conv2+bn2+relu (fp32 VALU, cheap) -> out.
__global__ __launch_bounds__(256, 4) void pif_mfma_kernel(
    const float* __restrict__ points, const float* __restrict__ imgf,
    const float* __restrict__ dist,   const int*   __restrict__ idx,
    const float* __restrict__ w1, const float* __restrict__ b1,
    const float* __restrict__ g1, const float* __restrict__ be1,
    const float* __restrict__ m1, const float* __restrict__ v1,
    const float* __restrict__ w2, const float* __restrict__ b2,
    const float* __restrict__ g2, const float* __restrict__ be2,
    const float* __restrict__ m2, const float* __restrict__ v2,
    float* __restrict__ out)
{
    __shared__ u32   x_lds[POS * XSTR];     // 34816 B
    __shared__ float pooled[NT][PPAD];      //  4864 B (total 39680 -> 4 blocks/CU)

    const int t   = threadIdx.x;
    const int tpb = N_ / NT;
    const int b   = blockIdx.x / tpb;
    const int n0  = (blockIdx.x % tpb) * NT;
    const int k   = t & 15, ln = t >> 4, n = n0 + ln;

    // ---------------- Phase A: build X row (bf16) ----------------
    const int   base_nk = (b * N_ + n) * K_ + k;
    const int   j  = idx[base_nk];
    const float dv = dist[base_nk];
    const int   pb = (b * N_ + n) * 3;
    const float px = points[pb], py = points[pb + 1], pz = points[pb + 2];
    const int   qb = (b * N_ + j) * 3;
    const float qx = points[qb], qy = points[qb + 1], qz = points[qb + 2];

    u32* row = &x_lds[t * XSTR];
    row[0] = pkbf(px, py);
    row[1] = pkbf(pz, qx);
    row[2] = pkbf(qy, qz);
    row[3] = pkbf(px - qx, py - qy);
    row[4] = pkbf(pz - qz, dv);

    const float* ip = imgf + (size_t)b * C_IMG * NK + (n * K_ + k);
    #pragma unroll
    for (int c0 = 0; c0 < C_IMG; c0 += CHUNK) {
        float xv[CHUNK];
        #pragma unroll
        for (int jj = 0; jj < CHUNK; ++jj) xv[jj] = ip[(c0 + jj) * NK];
        row[5 + c0 / 2    ] = pkbf(xv[0], xv[1]);
        row[5 + c0 / 2 + 1] = pkbf(xv[2], xv[3]);
        row[5 + c0 / 2 + 2] = pkbf(xv[4], xv[5]);
    }

    const int w = t >> 6, lane = t & 63, m16 = lane & 15, quad = lane >> 4;

    // B-frags: B[k=c][n=o], lane n=m16 reads w1[o][c..c+7] (row-major, contiguous)
    short8 bfrag[2][2];
    float  inv1v[2], add1v[2];
    #pragma unroll
    for (int ot = 0; ot < 2; ++ot) {
        const int o = ot * 16 + m16;
        #pragma unroll
        for (int kc = 0; kc < 2; ++kc) {
            const float* wr = w1 + o * C1 + kc * 32 + quad * 8;
            union { u32 u[4]; short8 v; } bf;
            bf.u[0] = pkbf(wr[0], wr[1]); bf.u[1] = pkbf(wr[2], wr[3]);
            bf.u[2] = pkbf(wr[4], wr[5]); bf.u[3] = pkbf(wr[6], wr[7]);
            bfrag[ot][kc] = bf.v;
        }
        const float iv = g1[o] * rsqrtf(v1[o] + BN_EPS);
        inv1v[ot] = iv;
        add1v[ot] = be1[o] - m1[o] * iv + b1[o] * iv;
    }

    // ep channels of pooled (max == mean == value)
    if (t < 48) {
        const int nn = t & 15, jj = t >> 4;
        const float v = points[(b * N_ + n0 + nn) * 3 + jj];
        pooled[nn][32 + jj] = v;
        pooled[nn][67 + jj] = v;
    }

    __syncthreads();

    // ---------------- Phase M: MFMA conv1 ----------------
    f32x4 acc[4][2];
    #pragma unroll
    for (int mt = 0; mt < 4; ++mt)
        #pragma unroll
        for (int ot = 0; ot < 2; ++ot)
            acc[mt][ot] = (f32x4){0.f, 0.f, 0.f, 0.f};

    #pragma unroll
    for (int mt = 0; mt < 4; ++mt) {
        #pragma unroll
        for (int kc = 0; kc < 2; ++kc) {
            // A[m=lane&15][c = kc*32 + quad*8 + j]: two b64 LDS reads
            const u32* r2 = &x_lds[(w * 64 + mt * 16 + m16) * XSTR + kc * 16 + quad * 4];
            uint2 a0 = *(const uint2*)r2;
            uint2 a1 = *(const uint2*)(r2 + 2);
            union { u32 u[4]; short8 v; } af;
            af.u[0] = a0.x; af.u[1] = a0.y; af.u[2] = a1.x; af.u[3] = a1.y;
            acc[mt][0] = __builtin_amdgcn_mfma_f32_16x16x32_bf16(af.v, bfrag[0][kc], acc[mt][0], 0, 0, 0);
            acc[mt][1] = __builtin_amdgcn_mfma_f32_16x16x32_bf16(af.v, bfrag[1][kc], acc[mt][1], 0, 0, 0);
        }
    }

    // BN1 + ReLU + pool over k (k = quad*4 + reg within mtile)
    #pragma unroll
    for (int mt = 0; mt < 4; ++mt) {
        #pragma unroll
        for (int ot = 0; ot < 2; ++ot) {
            float mx = 0.f, sm = 0.f;
            #pragma unroll
            for (int r = 0; r < 4; ++r) {
                float hv = fmaf(acc[mt][ot][r], inv1v[ot], add1v[ot]);
                hv = fmaxf(hv, 0.f);
                mx = fmaxf(mx, hv);
                sm += hv;
            }
            mx = fmaxf(mx, __shfl_xor(mx, 16));
            mx = fmaxf(mx, __shfl_xor(mx, 32));
            sm += __shfl_xor(sm, 16);
            sm += __shfl_xor(sm, 32);
            if (quad == 0) {
                const int nn = w * 4 + mt;
                pooled[nn][ot * 16 + m16]      = mx;
                pooled[nn][35 + ot * 16 + m16] = sm * (1.f / 16.f);
            }
        }
    }
    __syncthreads();

    // ---------------- Phase C: conv2 + bn2 + relu (fp32) ----------------
    #pragma unroll
    for (int r = 0; r < 2; ++r) {
        const int nn = t & 15;
        const int o  = (t >> 4) + r * 16;
        const float* wr = w2 + o * C2;
        float a0 = 0.f, a1 = 0.f;
        #pragma unroll
        for (int c = 0; c < C2; c += 2) {
            a0 = fmaf(wr[c],     pooled[nn][c],     a0);
            a1 = fmaf(wr[c + 1], pooled[nn][c + 1], a1);
        }
        const float acc2 = a0 + a1;
        const float iv = g2[o] * rsqrtf(v2[o] + BN_EPS);
        float ov = fmaf(acc2 + b2[o], iv, be2[o] - m2[o] * iv);
        ov = fmaxf(ov, 0.f);
        out[(b * CO + o) * N_ + n0 + nn] = ov;
    }
}

extern "C" void kernel_launch(void* const* d_in, const int* in_sizes, int n_in,
                              void* d_out, int out_size, void* d_ws, size_t ws_size,
                              hipStream_t stream) {
    const float* points = (const float*)d_in[0];
    const float* imgf   = (const float*)d_in[1];
    const float* dist   = (const float*)d_in[2];
    const int*   idx    = (const int*)  d_in[3];
    const float* w1     = (const float*)d_in[4];
    const float* b1     = (const float*)d_in[5];
    const float* g1     = (const float*)d_in[6];
    const float* be1    = (const float*)d_in[7];
    const float* m1     = (const float*)d_in[8];
    const float* v1     = (const float*)d_in[9];
    const float* w2     = (const float*)d_in[10];
    const float* b2     = (const float*)d_in[11];
    const float* g2     = (const float*)d_in[12];
    const float* be2    = (const float*)d_in[13];
    const float* m2     = (const float*)d_in[14];
    const float* v2     = (const float*)d_in[15];
    float* out          = (float*)d_out;

    const int blocks = B_ * (N_ / NT);       // 4096
    pif_mfma_kernel<<<blocks, 256, 0, stream>>>(
        points, imgf, dist, idx,
        w1, b1, g1, be1, m1, v1,
        w2, b2, g2, be2, m2, v2, out);
}